// Round 4
// baseline (199.139 us; speedup 1.0000x reference)
//
#include <hip/hip_runtime.h>
#include <math.h>

#define N 4096
#define D 256
#define HALF 2048
#define MARGIN 0.3f

#define BM 64        // block tile (rows == cols)
#define NTJ 32       // tiles per dimension (HALF / BM)

typedef __attribute__((ext_vector_type(8))) short bf16x8;  // 8 bf16 = 4 VGPRs
typedef __attribute__((ext_vector_type(4))) float f32x4;   // MFMA C/D

// Completion counters: zero-initialized at module load, self-resetting each
// launch (finisher subtracts the full count), so hipGraph replay is safe.
__device__ unsigned int g_row_cnt[NTJ];
__device__ unsigned int g_col_cnt[NTJ];
__device__ unsigned int g_fin_cnt;

__device__ __forceinline__ unsigned short f2bf(float x) {
    unsigned int u = __float_as_uint(x);
    return (unsigned short)((u + 0x7fffu + ((u >> 16) & 1u)) >> 16);
}

// ---------------------------------------------------------------------------
// Single kernel, 1024 independent blocks (no cooperative launch, no global
// barrier anywhere):
//   1. inline-normalize the block's own 64+64 rows (fp32, same math as the
//      verified k_norm), write bf16 straight into LDS with the verified XOR
//      swizzle (slot = r*32 + (g ^ (r&7)) in 16B granules); sq -> LDS.
//   2. verified MFMA core + distance epilogue + LDS max/min reduce.
//   3. per-strip partial stores (disjoint -> no init needed on poisoned ws).
//   4. strip completion counters: last block of row-strip bi reduces+relu's
//      rows bi*64..+63 (wave 0); last of col-strip bj its second-half rows
//      (wave 1). 64th strip finisher sums 64 strip partials in FIXED order.
// ---------------------------------------------------------------------------
__global__ __launch_bounds__(256, 2) void k_all(const float* __restrict__ in,
                                                const int* __restrict__ tg,
                                                int* __restrict__ rp_ap,
                                                int* __restrict__ rp_an,
                                                int* __restrict__ cp_ap,
                                                int* __restrict__ cp_an,
                                                float* __restrict__ strip_sum,
                                                float* __restrict__ out) {
    __shared__ unsigned short As[BM * D];   // 32 KB
    __shared__ unsigned short Bs[BM * D];   // 32 KB
    __shared__ int sra[BM], srn[BM], sca[BM], scn[BM];
    __shared__ float sqA[BM], sqB[BM];

    const int bi = blockIdx.y, bj = blockIdx.x;
    const int I0 = bi * BM;   // first-half rows
    const int J0 = bj * BM;   // second-half rows (= output cols)
    const int tid = threadIdx.x;
    const int wave = tid >> 6, lane = tid & 63;
    const int wm = wave >> 1, wn = wave & 1;   // 2x2 wave grid, 32x32 each
    const int lrow = lane & 15, lquad = lane >> 4;

    if (tid < BM) {           // init LDS reducers (visible after 1st barrier)
        sra[tid] = 0; srn[tid] = 0x7f800000;
        sca[tid] = 0; scn[tid] = 0x7f800000;
    }

    // ---- phase 1: inline normalize -> swizzled bf16 LDS tiles -------------
    // lane covers fp32 elems [lane*4, lane*4+4) = bf16 granule g=lane>>1,
    // half h=lane&1. Swizzled slot: r*32 + (g ^ (r&7)), 16B granules.
    const int g = lane >> 1, h = lane & 1;
#pragma unroll 2
    for (int p = 0; p < 16; ++p) {
        const int r = wave * 16 + p;       // local row handled by this wave
        {   // A row: global row I0 + r
            const float4 v = *(const float4*)&in[(size_t)(I0 + r) * D + lane * 4];
            float s = v.x * v.x + v.y * v.y + v.z * v.z + v.w * v.w;
#pragma unroll
            for (int o = 1; o < 64; o <<= 1) s += __shfl_xor(s, o, 64);
            float nrm = sqrtf(s);
            float inv = 1.0f / (nrm + 1e-6f);
            ushort4 o4;
            o4.x = f2bf(v.x * inv); o4.y = f2bf(v.y * inv);
            o4.z = f2bf(v.z * inv); o4.w = f2bf(v.w * inv);
            *(ushort4*)&As[(r * 32 + (g ^ (r & 7))) * 8 + h * 4] = o4;
            if (lane == 0) { float q = nrm * inv; sqA[r] = q * q; }
        }
        {   // B row: global row HALF + J0 + r
            const float4 v = *(const float4*)&in[(size_t)(HALF + J0 + r) * D + lane * 4];
            float s = v.x * v.x + v.y * v.y + v.z * v.z + v.w * v.w;
#pragma unroll
            for (int o = 1; o < 64; o <<= 1) s += __shfl_xor(s, o, 64);
            float nrm = sqrtf(s);
            float inv = 1.0f / (nrm + 1e-6f);
            ushort4 o4;
            o4.x = f2bf(v.x * inv); o4.y = f2bf(v.y * inv);
            o4.z = f2bf(v.z * inv); o4.w = f2bf(v.w * inv);
            *(ushort4*)&Bs[(r * 32 + (g ^ (r & 7))) * 8 + h * 4] = o4;
            if (lane == 0) { float q = nrm * inv; sqB[r] = q * q; }
        }
    }
    __syncthreads();

    // ---- phase 2: verified MFMA core over full K --------------------------
    f32x4 acc[2][2];
#pragma unroll
    for (int a = 0; a < 2; ++a)
#pragma unroll
        for (int b = 0; b < 2; ++b) acc[a][b] = (f32x4){0.f, 0.f, 0.f, 0.f};

#pragma unroll
    for (int kk = 0; kk < 8; ++kk) {
        bf16x8 af[2], bfr[2];
#pragma unroll
        for (int mi = 0; mi < 2; ++mi) {
            const int r = wm * 32 + mi * 16 + lrow;
            const int s = r * 32 + ((kk * 4 + lquad) ^ (r & 7));
            af[mi] = *(const bf16x8*)&As[s * 8];
        }
#pragma unroll
        for (int nj = 0; nj < 2; ++nj) {
            const int r = wn * 32 + nj * 16 + lrow;
            const int s = r * 32 + ((kk * 4 + lquad) ^ (r & 7));
            bfr[nj] = *(const bf16x8*)&Bs[s * 8];
        }
#pragma unroll
        for (int mi = 0; mi < 2; ++mi)
#pragma unroll
            for (int nj = 0; nj < 2; ++nj)
                acc[mi][nj] = __builtin_amdgcn_mfma_f32_16x16x32_bf16(
                    af[mi], bfr[nj], acc[mi][nj], 0, 0, 0);
    }

    // ---- epilogue: distances + masked max/min (verified) ------------------
    // C/D layout: col = lane&15, row = lquad*4 + reg   (per 16x16 tile)
    float sqi[2][4], sqj[2];
    int tgi[2][4], tgj[2];
#pragma unroll
    for (int mi = 0; mi < 2; ++mi)
#pragma unroll
        for (int r = 0; r < 4; ++r) {
            int lr = wm * 32 + mi * 16 + lquad * 4 + r;
            sqi[mi][r] = sqA[lr];
            tgi[mi][r] = tg[I0 + lr];
        }
#pragma unroll
    for (int nj = 0; nj < 2; ++nj) {
        int lc = wn * 32 + nj * 16 + lrow;
        sqj[nj] = sqB[lc];
        tgj[nj] = tg[HALF + J0 + lc];
    }

    const float INF = __int_as_float(0x7f800000);
    float rap[2][4], ran[2][4], capv[2], canv[2];
#pragma unroll
    for (int mi = 0; mi < 2; ++mi)
#pragma unroll
        for (int r = 0; r < 4; ++r) { rap[mi][r] = 0.f; ran[mi][r] = INF; }
#pragma unroll
    for (int nj = 0; nj < 2; ++nj) { capv[nj] = 0.f; canv[nj] = INF; }

#pragma unroll
    for (int mi = 0; mi < 2; ++mi)
#pragma unroll
        for (int nj = 0; nj < 2; ++nj)
#pragma unroll
            for (int r = 0; r < 4; ++r) {
                float d2 = sqi[mi][r] + sqj[nj] - 2.0f * acc[mi][nj][r];
                float d = sqrtf(fmaxf(d2, 1e-6f));
                if (tgi[mi][r] == tgj[nj]) {
                    rap[mi][r] = fmaxf(rap[mi][r], d);
                    capv[nj] = fmaxf(capv[nj], d);
                } else {
                    ran[mi][r] = fminf(ran[mi][r], d);
                    canv[nj] = fminf(canv[nj], d);
                }
            }

    // shuffle pre-reduce: rows across the 16 lanes sharing lquad
#pragma unroll
    for (int mi = 0; mi < 2; ++mi)
#pragma unroll
        for (int r = 0; r < 4; ++r) {
#pragma unroll
            for (int o = 1; o < 16; o <<= 1) {
                rap[mi][r] = fmaxf(rap[mi][r], __shfl_xor(rap[mi][r], o, 64));
                ran[mi][r] = fminf(ran[mi][r], __shfl_xor(ran[mi][r], o, 64));
            }
        }
    // cols across the 4 quads
#pragma unroll
    for (int nj = 0; nj < 2; ++nj) {
#pragma unroll
        for (int o = 16; o < 64; o <<= 1) {
            capv[nj] = fmaxf(capv[nj], __shfl_xor(capv[nj], o, 64));
            canv[nj] = fminf(canv[nj], __shfl_xor(canv[nj], o, 64));
        }
    }

    if (lrow == 0) {
#pragma unroll
        for (int mi = 0; mi < 2; ++mi)
#pragma unroll
            for (int r = 0; r < 4; ++r) {
                int lr = wm * 32 + mi * 16 + lquad * 4 + r;
                atomicMax(&sra[lr], __float_as_int(rap[mi][r]));
                atomicMin(&srn[lr], __float_as_int(ran[mi][r]));
            }
    }
    if (lquad == 0) {
#pragma unroll
        for (int nj = 0; nj < 2; ++nj) {
            int lc = wn * 32 + nj * 16 + lrow;
            atomicMax(&sca[lc], __float_as_int(capv[nj]));
            atomicMin(&scn[lc], __float_as_int(canv[nj]));
        }
    }
    __syncthreads();

    // ---- phase 3: disjoint per-strip partial stores -----------------------
    if (tid < BM) {
        rp_ap[bi * (NTJ * BM) + bj * BM + tid] = sra[tid];
        rp_an[bi * (NTJ * BM) + bj * BM + tid] = srn[tid];
        cp_ap[bj * (NTJ * BM) + bi * BM + tid] = sca[tid];
        cp_an[bj * (NTJ * BM) + bi * BM + tid] = scn[tid];
    }
    __threadfence();
    __syncthreads();

    // ---- phase 4: strip finishers (wave0 = row strip, wave1 = col strip) --
    if (wave == 0) {
        int fin = 0;
        if (lane == 0) {
            unsigned int old = __hip_atomic_fetch_add(
                &g_row_cnt[bi], 1u, __ATOMIC_ACQ_REL, __HIP_MEMORY_SCOPE_AGENT);
            fin = (old == NTJ - 1);
            if (fin)
                __hip_atomic_fetch_add(&g_row_cnt[bi], 0u - (unsigned)NTJ,
                                       __ATOMIC_RELAXED, __HIP_MEMORY_SCOPE_AGENT);
        }
        fin = __shfl(fin, 0, 64);
        if (fin) {
            __threadfence();
            int apb = 0, anb = 0x7f800000;
            const int base = bi * (NTJ * BM) + lane;
#pragma unroll
            for (int b = 0; b < NTJ; ++b) {
                apb = max(apb, __hip_atomic_load(&rp_ap[base + b * BM],
                           __ATOMIC_RELAXED, __HIP_MEMORY_SCOPE_AGENT));
                anb = min(anb, __hip_atomic_load(&rp_an[base + b * BM],
                           __ATOMIC_RELAXED, __HIP_MEMORY_SCOPE_AGENT));
            }
            float dap = __int_as_float(apb);
            float dan = (anb == 0x7f800000) ? 1.0f : __int_as_float(anb);
            float v = dap - dan + MARGIN;
            float sl = (v > 0.f) ? v : 0.f;
#pragma unroll
            for (int o = 1; o < 64; o <<= 1) sl += __shfl_xor(sl, o, 64);
            if (lane == 0) {
                __hip_atomic_store(&strip_sum[bi], sl,
                                   __ATOMIC_RELAXED, __HIP_MEMORY_SCOPE_AGENT);
                __threadfence();
                unsigned int fo = __hip_atomic_fetch_add(
                    &g_fin_cnt, 1u, __ATOMIC_ACQ_REL, __HIP_MEMORY_SCOPE_AGENT);
                if (fo == 2u * NTJ - 1u) {
                    __hip_atomic_fetch_add(&g_fin_cnt, 0u - 2u * (unsigned)NTJ,
                                           __ATOMIC_RELAXED, __HIP_MEMORY_SCOPE_AGENT);
                    __threadfence();
                    float t[2 * NTJ];
#pragma unroll
                    for (int b = 0; b < 2 * NTJ; ++b)
                        t[b] = __hip_atomic_load(&strip_sum[b],
                                 __ATOMIC_RELAXED, __HIP_MEMORY_SCOPE_AGENT);
                    float tot = 0.f;
#pragma unroll
                    for (int b = 0; b < 2 * NTJ; ++b) tot += t[b];
                    out[0] = tot / (float)N;
                }
            }
        }
    } else if (wave == 1) {
        int fin = 0;
        if (lane == 0) {
            unsigned int old = __hip_atomic_fetch_add(
                &g_col_cnt[bj], 1u, __ATOMIC_ACQ_REL, __HIP_MEMORY_SCOPE_AGENT);
            fin = (old == NTJ - 1);
            if (fin)
                __hip_atomic_fetch_add(&g_col_cnt[bj], 0u - (unsigned)NTJ,
                                       __ATOMIC_RELAXED, __HIP_MEMORY_SCOPE_AGENT);
        }
        fin = __shfl(fin, 0, 64);
        if (fin) {
            __threadfence();
            int apb = 0, anb = 0x7f800000;
            const int base = bj * (NTJ * BM) + lane;
#pragma unroll
            for (int b = 0; b < NTJ; ++b) {
                apb = max(apb, __hip_atomic_load(&cp_ap[base + b * BM],
                           __ATOMIC_RELAXED, __HIP_MEMORY_SCOPE_AGENT));
                anb = min(anb, __hip_atomic_load(&cp_an[base + b * BM],
                           __ATOMIC_RELAXED, __HIP_MEMORY_SCOPE_AGENT));
            }
            float dap = __int_as_float(apb);
            float dan = (anb == 0x7f800000) ? 1.0f : __int_as_float(anb);
            float v = dap - dan + MARGIN;
            float sl = (v > 0.f) ? v : 0.f;
#pragma unroll
            for (int o = 1; o < 64; o <<= 1) sl += __shfl_xor(sl, o, 64);
            if (lane == 0) {
                __hip_atomic_store(&strip_sum[NTJ + bj], sl,
                                   __ATOMIC_RELAXED, __HIP_MEMORY_SCOPE_AGENT);
                __threadfence();
                unsigned int fo = __hip_atomic_fetch_add(
                    &g_fin_cnt, 1u, __ATOMIC_ACQ_REL, __HIP_MEMORY_SCOPE_AGENT);
                if (fo == 2u * NTJ - 1u) {
                    __hip_atomic_fetch_add(&g_fin_cnt, 0u - 2u * (unsigned)NTJ,
                                           __ATOMIC_RELAXED, __HIP_MEMORY_SCOPE_AGENT);
                    __threadfence();
                    float t[2 * NTJ];
#pragma unroll
                    for (int b = 0; b < 2 * NTJ; ++b)
                        t[b] = __hip_atomic_load(&strip_sum[b],
                                 __ATOMIC_RELAXED, __HIP_MEMORY_SCOPE_AGENT);
                    float tot = 0.f;
#pragma unroll
                    for (int b = 0; b < 2 * NTJ; ++b) tot += t[b];
                    out[0] = tot / (float)N;
                }
            }
        }
    }
}

extern "C" void kernel_launch(void* const* d_in, const int* in_sizes, int n_in,
                              void* d_out, int out_size, void* d_ws, size_t ws_size,
                              hipStream_t stream) {
    const float* in = (const float*)d_in[0];
    const int* tg = (const int*)d_in[1];
    float* out = (float*)d_out;

    int* rp_ap = (int*)d_ws;                         // NTJ*HALF ints each
    int* rp_an = rp_ap + NTJ * HALF;
    int* cp_ap = rp_an + NTJ * HALF;
    int* cp_an = cp_ap + NTJ * HALF;
    float* strip_sum = (float*)(cp_an + NTJ * HALF); // 64 floats

    k_all<<<dim3(NTJ, NTJ), 256, 0, stream>>>(in, tg, rp_ap, rp_an,
                                              cp_ap, cp_an, strip_sum, out);
}

// Round 5
// 164.789 us; speedup vs baseline: 1.2084x; 1.2084x over previous
//
#include <hip/hip_runtime.h>
#include <math.h>

#define N 4096
#define D 256
#define HALF 2048
#define MARGIN 0.3f

#define BM 64        // block tile (rows == cols)
#define NTJ 32       // tiles per dimension (HALF / BM)

typedef __attribute__((ext_vector_type(8))) short bf16x8;  // 8 bf16 = 4 VGPRs
typedef __attribute__((ext_vector_type(4))) float f32x4;   // MFMA C/D

typedef __attribute__((address_space(1))) const unsigned int gas_uint;
typedef __attribute__((address_space(3))) unsigned int las_uint;

// Strip-completion counters: zero at module load; finishers self-reset by
// subtracting the full count, so hipGraph replay sees zeros again. This
// exact pattern validated in round 4 (absmax 0 across all iterations).
__device__ unsigned int g_row_cnt[NTJ];
__device__ unsigned int g_col_cnt[NTJ];
__device__ unsigned int g_fin_cnt;

__device__ __forceinline__ void gld16(const unsigned short* g, unsigned short* l) {
    // async global->LDS, 16 B per lane; LDS dest = wave-uniform base + lane*16
    __builtin_amdgcn_global_load_lds((gas_uint*)g, (las_uint*)l, 16, 0, 0);
}

__device__ __forceinline__ unsigned short f2bf(float x) {
    unsigned int u = __float_as_uint(x);
    return (unsigned short)((u + 0x7fffu + ((u >> 16) & 1u)) >> 16);
}

// ---------------------------------------------------------------------------
// Kernel 1 (unchanged from the 73 µs champion): row L2-normalize -> bf16,
// sq (fp32), ap/an init. One wave per row; no LDS, no barrier.
// ---------------------------------------------------------------------------
__global__ __launch_bounds__(256) void k_norm(const float* __restrict__ in,
                                              unsigned short* __restrict__ xnb,
                                              float* __restrict__ sq,
                                              int* __restrict__ ap,
                                              int* __restrict__ an) {
    const int row = blockIdx.x * 4 + (threadIdx.x >> 6);
    const int lane = threadIdx.x & 63;
    const float4 v = *(const float4*)&in[(size_t)row * D + lane * 4];
    float s = v.x * v.x + v.y * v.y + v.z * v.z + v.w * v.w;
#pragma unroll
    for (int o = 1; o < 64; o <<= 1) s += __shfl_xor(s, o, 64);
    float nrm = sqrtf(s);
    float inv = 1.0f / (nrm + 1e-6f);
    ushort4 o4;
    o4.x = f2bf(v.x * inv);
    o4.y = f2bf(v.y * inv);
    o4.z = f2bf(v.z * inv);
    o4.w = f2bf(v.w * inv);
    *(ushort4*)&xnb[(size_t)row * D + lane * 4] = o4;
    if (lane == 0) {
        float q = nrm * inv;
        sq[row] = q * q;
        ap[row] = 0;            // == bits(0.0f), the pos_any-false fallback
        an[row] = 0x7f800000;   // +inf sentinel for neg_any-false
    }
}

// ---------------------------------------------------------------------------
// Kernel 2: the verified 73 µs k_tile (MFMA core, epilogue, LDS reduce,
// global-atomic tail ALL byte-identical), plus a fused distributed loss
// finisher: the last block of each 64-row strip computes that strip's
// relu-sum from the now-final ap/an; the 64th strip finisher sums the 64
// strip partials in fixed order -> deterministic loss. No third launch.
// ---------------------------------------------------------------------------
__global__ __launch_bounds__(256, 2) void k_tile(const unsigned short* __restrict__ xnb,
                                                 const float* __restrict__ sq,
                                                 const int* __restrict__ tg,
                                                 int* __restrict__ ap,
                                                 int* __restrict__ an,
                                                 float* __restrict__ strip_sum,
                                                 float* __restrict__ out) {
    __shared__ unsigned short As[BM * D];   // 32 KB
    __shared__ unsigned short Bs[BM * D];   // 32 KB
    __shared__ int sra[BM], srn[BM], sca[BM], scn[BM];

    const int bi = blockIdx.y, bj = blockIdx.x;
    const int I0 = bi * BM;   // first-half rows
    const int J0 = bj * BM;   // second-half rows (= output cols)
    const int tid = threadIdx.x;
    const int wave = tid >> 6, lane = tid & 63;
    const int wm = wave >> 1, wn = wave & 1;   // 2x2 wave grid, 32x32 each
    const int lrow = lane & 15, lquad = lane >> 4;

    const unsigned short* Ag = xnb + (size_t)I0 * D;
    const unsigned short* Bg = xnb + (size_t)(HALF + J0) * D;

    // ---- stage full 64x256 tiles, pre-swizzled source, linear LDS dest ----
#pragma unroll
    for (int i = 0; i < 8; ++i) {
        const int ch = i * 4 + wave;           // 1 KB chunk index, wave-uniform
        const int e = ch * 64 + lane;          // this lane's linear 16B slot
        const int row = e >> 5;
        const int sc = (e & 31) ^ (row & 7);   // inverse-swizzled source colgrp
        gld16(Ag + row * D + sc * 8, &As[ch * 512]);
        gld16(Bg + row * D + sc * 8, &Bs[ch * 512]);
    }
    if (tid < BM) {           // init LDS reducers while loads fly
        sra[tid] = 0; srn[tid] = 0x7f800000;
        sca[tid] = 0; scn[tid] = 0x7f800000;
    }
    asm volatile("s_waitcnt vmcnt(0)" ::: "memory");
    __syncthreads();

    // ---- single uninterrupted ds_read + MFMA stream over full K ----------
    f32x4 acc[2][2];
#pragma unroll
    for (int a = 0; a < 2; ++a)
#pragma unroll
        for (int b = 0; b < 2; ++b) acc[a][b] = (f32x4){0.f, 0.f, 0.f, 0.f};

#pragma unroll
    for (int kk = 0; kk < 8; ++kk) {
        bf16x8 af[2], bfr[2];
#pragma unroll
        for (int mi = 0; mi < 2; ++mi) {
            const int r = wm * 32 + mi * 16 + lrow;
            const int s = r * 32 + ((kk * 4 + lquad) ^ (r & 7));
            af[mi] = *(const bf16x8*)&As[s * 8];
        }
#pragma unroll
        for (int nj = 0; nj < 2; ++nj) {
            const int r = wn * 32 + nj * 16 + lrow;
            const int s = r * 32 + ((kk * 4 + lquad) ^ (r & 7));
            bfr[nj] = *(const bf16x8*)&Bs[s * 8];
        }
#pragma unroll
        for (int mi = 0; mi < 2; ++mi)
#pragma unroll
            for (int nj = 0; nj < 2; ++nj)
                acc[mi][nj] = __builtin_amdgcn_mfma_f32_16x16x32_bf16(
                    af[mi], bfr[nj], acc[mi][nj], 0, 0, 0);
    }

    // ---- epilogue: distances + masked max/min -----------------------------
    // C/D layout: col = lane&15, row = lquad*4 + reg   (per 16x16 tile)
    float sqi[2][4], sqj[2];
    int tgi[2][4], tgj[2];
#pragma unroll
    for (int mi = 0; mi < 2; ++mi)
#pragma unroll
        for (int r = 0; r < 4; ++r) {
            int gi = I0 + wm * 32 + mi * 16 + lquad * 4 + r;
            sqi[mi][r] = sq[gi];
            tgi[mi][r] = tg[gi];
        }
#pragma unroll
    for (int nj = 0; nj < 2; ++nj) {
        int gj = HALF + J0 + wn * 32 + nj * 16 + lrow;
        sqj[nj] = sq[gj];
        tgj[nj] = tg[gj];
    }

    const float INF = __int_as_float(0x7f800000);
    float rap[2][4], ran[2][4], capv[2], canv[2];
#pragma unroll
    for (int mi = 0; mi < 2; ++mi)
#pragma unroll
        for (int r = 0; r < 4; ++r) { rap[mi][r] = 0.f; ran[mi][r] = INF; }
#pragma unroll
    for (int nj = 0; nj < 2; ++nj) { capv[nj] = 0.f; canv[nj] = INF; }

#pragma unroll
    for (int mi = 0; mi < 2; ++mi)
#pragma unroll
        for (int nj = 0; nj < 2; ++nj)
#pragma unroll
            for (int r = 0; r < 4; ++r) {
                float d2 = sqi[mi][r] + sqj[nj] - 2.0f * acc[mi][nj][r];
                float d = sqrtf(fmaxf(d2, 1e-6f));
                if (tgi[mi][r] == tgj[nj]) {
                    rap[mi][r] = fmaxf(rap[mi][r], d);
                    capv[nj] = fmaxf(capv[nj], d);
                } else {
                    ran[mi][r] = fminf(ran[mi][r], d);
                    canv[nj] = fminf(canv[nj], d);
                }
            }

    // shuffle pre-reduce: rows across the 16 lanes sharing lquad
#pragma unroll
    for (int mi = 0; mi < 2; ++mi)
#pragma unroll
        for (int r = 0; r < 4; ++r) {
#pragma unroll
            for (int o = 1; o < 16; o <<= 1) {
                rap[mi][r] = fmaxf(rap[mi][r], __shfl_xor(rap[mi][r], o, 64));
                ran[mi][r] = fminf(ran[mi][r], __shfl_xor(ran[mi][r], o, 64));
            }
        }
    // cols across the 4 quads
#pragma unroll
    for (int nj = 0; nj < 2; ++nj) {
#pragma unroll
        for (int o = 16; o < 64; o <<= 1) {
            capv[nj] = fmaxf(capv[nj], __shfl_xor(capv[nj], o, 64));
            canv[nj] = fminf(canv[nj], __shfl_xor(canv[nj], o, 64));
        }
    }

    if (lrow == 0) {  // one lane per row; 2-way contention (wn)
#pragma unroll
        for (int mi = 0; mi < 2; ++mi)
#pragma unroll
            for (int r = 0; r < 4; ++r) {
                int lr = wm * 32 + mi * 16 + lquad * 4 + r;
                atomicMax(&sra[lr], __float_as_int(rap[mi][r]));
                atomicMin(&srn[lr], __float_as_int(ran[mi][r]));
            }
    }
    if (lquad == 0) {  // one lane per col; 2-way contention (wm)
#pragma unroll
        for (int nj = 0; nj < 2; ++nj) {
            int lc = wn * 32 + nj * 16 + lrow;
            atomicMax(&sca[lc], __float_as_int(capv[nj]));
            atomicMin(&scn[lc], __float_as_int(canv[nj]));
        }
    }
    __syncthreads();
    if (tid < BM) {   // device-scope atomics into ap/an (the 73 µs tail)
        atomicMax(&ap[I0 + tid], sra[tid]);
        atomicMin(&an[I0 + tid], srn[tid]);
        atomicMax(&ap[HALF + J0 + tid], sca[tid]);
        atomicMin(&an[HALF + J0 + tid], scn[tid]);
    }
    __threadfence();
    __syncthreads();

    // ---- fused loss finisher (round-4-validated machinery) ----------------
    // wave 0 -> row strip bi (rows I0..I0+63), wave 1 -> col strip bj
    // (rows HALF+J0..+63). Last block of a strip reduces it; 64th strip
    // finisher sums 64 partials in fixed order.
    if (wave < 2) {
        unsigned int* cnt = (wave == 0) ? &g_row_cnt[bi] : &g_col_cnt[bj];
        const int base = (wave == 0) ? I0 : HALF + J0;
        const int slot = (wave == 0) ? bi : NTJ + bj;
        int fin = 0;
        if (lane == 0) {
            unsigned int old = __hip_atomic_fetch_add(
                cnt, 1u, __ATOMIC_ACQ_REL, __HIP_MEMORY_SCOPE_AGENT);
            fin = (old == NTJ - 1);
            if (fin)   // self-reset for graph replay
                __hip_atomic_fetch_add(cnt, 0u - (unsigned)NTJ,
                                       __ATOMIC_RELAXED, __HIP_MEMORY_SCOPE_AGENT);
        }
        fin = __shfl(fin, 0, 64);
        if (fin) {
            __threadfence();
            int apb = __hip_atomic_load(&ap[base + lane],
                        __ATOMIC_RELAXED, __HIP_MEMORY_SCOPE_AGENT);
            int anb = __hip_atomic_load(&an[base + lane],
                        __ATOMIC_RELAXED, __HIP_MEMORY_SCOPE_AGENT);
            float dap = __int_as_float(apb);
            float dan = (anb == 0x7f800000) ? 1.0f : __int_as_float(anb);
            float v = dap - dan + MARGIN;
            float sl = (v > 0.f) ? v : 0.f;
#pragma unroll
            for (int o = 1; o < 64; o <<= 1) sl += __shfl_xor(sl, o, 64);
            if (lane == 0) {
                __hip_atomic_store(&strip_sum[slot], sl,
                                   __ATOMIC_RELAXED, __HIP_MEMORY_SCOPE_AGENT);
                __threadfence();
                unsigned int fo = __hip_atomic_fetch_add(
                    &g_fin_cnt, 1u, __ATOMIC_ACQ_REL, __HIP_MEMORY_SCOPE_AGENT);
                if (fo == 2u * NTJ - 1u) {
                    __hip_atomic_fetch_add(&g_fin_cnt, 0u - 2u * (unsigned)NTJ,
                                           __ATOMIC_RELAXED, __HIP_MEMORY_SCOPE_AGENT);
                    __threadfence();
                    float tot = 0.f;
#pragma unroll
                    for (int b = 0; b < 2 * NTJ; ++b)
                        tot += __hip_atomic_load(&strip_sum[b],
                                 __ATOMIC_RELAXED, __HIP_MEMORY_SCOPE_AGENT);
                    out[0] = tot / (float)N;
                }
            }
        }
    }
}

extern "C" void kernel_launch(void* const* d_in, const int* in_sizes, int n_in,
                              void* d_out, int out_size, void* d_ws, size_t ws_size,
                              hipStream_t stream) {
    const float* in = (const float*)d_in[0];
    const int* tg = (const int*)d_in[1];
    float* out = (float*)d_out;

    unsigned short* xnb = (unsigned short*)d_ws;     // N*D bf16 (2 MB)
    float* sq = (float*)(xnb + (size_t)N * D);       // N floats
    int* ap = (int*)(sq + N);                        // N ints
    int* an = ap + N;                                // N ints
    float* strip_sum = (float*)(an + N);             // 64 floats

    k_norm<<<N / 4, 256, 0, stream>>>(in, xnb, sq, ap, an);
    k_tile<<<dim3(NTJ, NTJ), 256, 0, stream>>>(xnb, sq, tg, ap, an,
                                               strip_sum, out);
}

// Round 6
// 78.695 us; speedup vs baseline: 2.5305x; 2.0940x over previous
//
#include <hip/hip_runtime.h>
#include <math.h>

#define N 4096
#define D 256
#define HALF 2048
#define MARGIN 0.3f

#define BM 64        // block tile (rows == cols)
#define NTJ 32       // tiles per dimension (HALF / BM)

typedef __attribute__((ext_vector_type(8))) short bf16x8;  // 8 bf16 = 4 VGPRs
typedef __attribute__((ext_vector_type(4))) float f32x4;   // MFMA C/D

typedef __attribute__((address_space(1))) const unsigned int gas_uint;
typedef __attribute__((address_space(3))) unsigned int las_uint;

// Strip-completion counters: zero at module load; finishers self-reset by
// subtracting the full count, so hipGraph replay sees zeros again.
// (Counter machinery validated correct in rounds 4/5; round 5 showed the
// per-block __threadfence — an agent-scope L2 writeback on gfx950 — was a
// ~90 µs cost. All cross-block data below is written with ATOMICS, which
// are performed at the coherent point; the vmcnt(0) drain that
// __syncthreads implies orders them before the counter increment, so no
// fence is needed.)
__device__ unsigned int g_row_cnt[NTJ];
__device__ unsigned int g_col_cnt[NTJ];
__device__ unsigned int g_fin_cnt;

__device__ __forceinline__ void gld16(const unsigned short* g, unsigned short* l) {
    // async global->LDS, 16 B per lane; LDS dest = wave-uniform base + lane*16
    __builtin_amdgcn_global_load_lds((gas_uint*)g, (las_uint*)l, 16, 0, 0);
}

__device__ __forceinline__ unsigned short f2bf(float x) {
    unsigned int u = __float_as_uint(x);
    return (unsigned short)((u + 0x7fffu + ((u >> 16) & 1u)) >> 16);
}

// ---------------------------------------------------------------------------
// Kernel 1 (unchanged from the 73 µs champion): row L2-normalize -> bf16,
// sq (fp32), ap/an init. One wave per row; no LDS, no barrier.
// ---------------------------------------------------------------------------
__global__ __launch_bounds__(256) void k_norm(const float* __restrict__ in,
                                              unsigned short* __restrict__ xnb,
                                              float* __restrict__ sq,
                                              int* __restrict__ ap,
                                              int* __restrict__ an) {
    const int row = blockIdx.x * 4 + (threadIdx.x >> 6);
    const int lane = threadIdx.x & 63;
    const float4 v = *(const float4*)&in[(size_t)row * D + lane * 4];
    float s = v.x * v.x + v.y * v.y + v.z * v.z + v.w * v.w;
#pragma unroll
    for (int o = 1; o < 64; o <<= 1) s += __shfl_xor(s, o, 64);
    float nrm = sqrtf(s);
    float inv = 1.0f / (nrm + 1e-6f);
    ushort4 o4;
    o4.x = f2bf(v.x * inv);
    o4.y = f2bf(v.y * inv);
    o4.z = f2bf(v.z * inv);
    o4.w = f2bf(v.w * inv);
    *(ushort4*)&xnb[(size_t)row * D + lane * 4] = o4;
    if (lane == 0) {
        float q = nrm * inv;
        sq[row] = q * q;
        ap[row] = 0;            // == bits(0.0f), the pos_any-false fallback
        an[row] = 0x7f800000;   // +inf sentinel for neg_any-false
    }
}

// ---------------------------------------------------------------------------
// Kernel 2: the verified k_tile (MFMA core, epilogue, LDS reduce, device-
// atomic tail all identical to the 73 µs champion) + fused loss finisher.
// NO __threadfence anywhere in the 1024-block main path.
// ---------------------------------------------------------------------------
__global__ __launch_bounds__(256, 2) void k_tile(const unsigned short* __restrict__ xnb,
                                                 const float* __restrict__ sq,
                                                 const int* __restrict__ tg,
                                                 int* __restrict__ ap,
                                                 int* __restrict__ an,
                                                 float* __restrict__ strip_sum,
                                                 float* __restrict__ out) {
    __shared__ unsigned short As[BM * D];   // 32 KB
    __shared__ unsigned short Bs[BM * D];   // 32 KB
    __shared__ int sra[BM], srn[BM], sca[BM], scn[BM];

    const int bi = blockIdx.y, bj = blockIdx.x;
    const int I0 = bi * BM;   // first-half rows
    const int J0 = bj * BM;   // second-half rows (= output cols)
    const int tid = threadIdx.x;
    const int wave = tid >> 6, lane = tid & 63;
    const int wm = wave >> 1, wn = wave & 1;   // 2x2 wave grid, 32x32 each
    const int lrow = lane & 15, lquad = lane >> 4;

    const unsigned short* Ag = xnb + (size_t)I0 * D;
    const unsigned short* Bg = xnb + (size_t)(HALF + J0) * D;

    // ---- stage full 64x256 tiles, pre-swizzled source, linear LDS dest ----
#pragma unroll
    for (int i = 0; i < 8; ++i) {
        const int ch = i * 4 + wave;           // 1 KB chunk index, wave-uniform
        const int e = ch * 64 + lane;          // this lane's linear 16B slot
        const int row = e >> 5;
        const int sc = (e & 31) ^ (row & 7);   // inverse-swizzled source colgrp
        gld16(Ag + row * D + sc * 8, &As[ch * 512]);
        gld16(Bg + row * D + sc * 8, &Bs[ch * 512]);
    }
    if (tid < BM) {           // init LDS reducers while loads fly
        sra[tid] = 0; srn[tid] = 0x7f800000;
        sca[tid] = 0; scn[tid] = 0x7f800000;
    }
    asm volatile("s_waitcnt vmcnt(0)" ::: "memory");
    __syncthreads();

    // ---- single uninterrupted ds_read + MFMA stream over full K ----------
    f32x4 acc[2][2];
#pragma unroll
    for (int a = 0; a < 2; ++a)
#pragma unroll
        for (int b = 0; b < 2; ++b) acc[a][b] = (f32x4){0.f, 0.f, 0.f, 0.f};

#pragma unroll
    for (int kk = 0; kk < 8; ++kk) {
        bf16x8 af[2], bfr[2];
#pragma unroll
        for (int mi = 0; mi < 2; ++mi) {
            const int r = wm * 32 + mi * 16 + lrow;
            const int s = r * 32 + ((kk * 4 + lquad) ^ (r & 7));
            af[mi] = *(const bf16x8*)&As[s * 8];
        }
#pragma unroll
        for (int nj = 0; nj < 2; ++nj) {
            const int r = wn * 32 + nj * 16 + lrow;
            const int s = r * 32 + ((kk * 4 + lquad) ^ (r & 7));
            bfr[nj] = *(const bf16x8*)&Bs[s * 8];
        }
#pragma unroll
        for (int mi = 0; mi < 2; ++mi)
#pragma unroll
            for (int nj = 0; nj < 2; ++nj)
                acc[mi][nj] = __builtin_amdgcn_mfma_f32_16x16x32_bf16(
                    af[mi], bfr[nj], acc[mi][nj], 0, 0, 0);
    }

    // ---- epilogue: distances + masked max/min -----------------------------
    // C/D layout: col = lane&15, row = lquad*4 + reg   (per 16x16 tile)
    float sqi[2][4], sqj[2];
    int tgi[2][4], tgj[2];
#pragma unroll
    for (int mi = 0; mi < 2; ++mi)
#pragma unroll
        for (int r = 0; r < 4; ++r) {
            int gi = I0 + wm * 32 + mi * 16 + lquad * 4 + r;
            sqi[mi][r] = sq[gi];
            tgi[mi][r] = tg[gi];
        }
#pragma unroll
    for (int nj = 0; nj < 2; ++nj) {
        int gj = HALF + J0 + wn * 32 + nj * 16 + lrow;
        sqj[nj] = sq[gj];
        tgj[nj] = tg[gj];
    }

    const float INF = __int_as_float(0x7f800000);
    float rap[2][4], ran[2][4], capv[2], canv[2];
#pragma unroll
    for (int mi = 0; mi < 2; ++mi)
#pragma unroll
        for (int r = 0; r < 4; ++r) { rap[mi][r] = 0.f; ran[mi][r] = INF; }
#pragma unroll
    for (int nj = 0; nj < 2; ++nj) { capv[nj] = 0.f; canv[nj] = INF; }

#pragma unroll
    for (int mi = 0; mi < 2; ++mi)
#pragma unroll
        for (int nj = 0; nj < 2; ++nj)
#pragma unroll
            for (int r = 0; r < 4; ++r) {
                float d2 = sqi[mi][r] + sqj[nj] - 2.0f * acc[mi][nj][r];
                float d = sqrtf(fmaxf(d2, 1e-6f));
                if (tgi[mi][r] == tgj[nj]) {
                    rap[mi][r] = fmaxf(rap[mi][r], d);
                    capv[nj] = fmaxf(capv[nj], d);
                } else {
                    ran[mi][r] = fminf(ran[mi][r], d);
                    canv[nj] = fminf(canv[nj], d);
                }
            }

    // shuffle pre-reduce: rows across the 16 lanes sharing lquad
#pragma unroll
    for (int mi = 0; mi < 2; ++mi)
#pragma unroll
        for (int r = 0; r < 4; ++r) {
#pragma unroll
            for (int o = 1; o < 16; o <<= 1) {
                rap[mi][r] = fmaxf(rap[mi][r], __shfl_xor(rap[mi][r], o, 64));
                ran[mi][r] = fminf(ran[mi][r], __shfl_xor(ran[mi][r], o, 64));
            }
        }
    // cols across the 4 quads
#pragma unroll
    for (int nj = 0; nj < 2; ++nj) {
#pragma unroll
        for (int o = 16; o < 64; o <<= 1) {
            capv[nj] = fmaxf(capv[nj], __shfl_xor(capv[nj], o, 64));
            canv[nj] = fminf(canv[nj], __shfl_xor(canv[nj], o, 64));
        }
    }

    if (lrow == 0) {  // one lane per row; 2-way contention (wn)
#pragma unroll
        for (int mi = 0; mi < 2; ++mi)
#pragma unroll
            for (int r = 0; r < 4; ++r) {
                int lr = wm * 32 + mi * 16 + lquad * 4 + r;
                atomicMax(&sra[lr], __float_as_int(rap[mi][r]));
                atomicMin(&srn[lr], __float_as_int(ran[mi][r]));
            }
    }
    if (lquad == 0) {  // one lane per col; 2-way contention (wm)
#pragma unroll
        for (int nj = 0; nj < 2; ++nj) {
            int lc = wn * 32 + nj * 16 + lrow;
            atomicMax(&sca[lc], __float_as_int(capv[nj]));
            atomicMin(&scn[lc], __float_as_int(canv[nj]));
        }
    }
    __syncthreads();
    if (tid < BM) {   // device-scope atomics into ap/an (performed at the
                      // coherent point -> cross-XCD visible, no fence needed)
        atomicMax(&ap[I0 + tid], sra[tid]);
        atomicMin(&an[I0 + tid], srn[tid]);
        atomicMax(&ap[HALF + J0 + tid], sca[tid]);
        atomicMin(&an[HALF + J0 + tid], scn[tid]);
    }
    // __syncthreads drains vmcnt(0): the atomics above are globally
    // performed before any lane of this block touches the counters.
    __syncthreads();

    // ---- fused loss finisher (64 of 1024 blocks do real work) -------------
    // wave 0 -> row strip bi (rows I0..+63), wave 1 -> col strip bj
    // (rows HALF+J0..+63). Last block of a strip reduces it; 64th strip
    // finisher sums 64 partials in fixed order (deterministic).
    if (wave < 2) {
        unsigned int* cnt = (wave == 0) ? &g_row_cnt[bi] : &g_col_cnt[bj];
        const int base = (wave == 0) ? I0 : HALF + J0;
        const int slot = (wave == 0) ? bi : NTJ + bj;
        int fin = 0;
        if (lane == 0) {
            unsigned int old = __hip_atomic_fetch_add(
                cnt, 1u, __ATOMIC_RELAXED, __HIP_MEMORY_SCOPE_AGENT);
            fin = (old == NTJ - 1);
            if (fin)   // self-reset for graph replay
                __hip_atomic_fetch_add(cnt, 0u - (unsigned)NTJ,
                                       __ATOMIC_RELAXED, __HIP_MEMORY_SCOPE_AGENT);
        }
        fin = __shfl(fin, 0, 64);
        if (fin) {
            // control-dependent on final count; agent-scope atomic loads
            // read the coherent point (bypass stale local caches).
            int apb = __hip_atomic_load(&ap[base + lane],
                        __ATOMIC_RELAXED, __HIP_MEMORY_SCOPE_AGENT);
            int anb = __hip_atomic_load(&an[base + lane],
                        __ATOMIC_RELAXED, __HIP_MEMORY_SCOPE_AGENT);
            float dap = __int_as_float(apb);
            float dan = (anb == 0x7f800000) ? 1.0f : __int_as_float(anb);
            float v = dap - dan + MARGIN;
            float sl = (v > 0.f) ? v : 0.f;
#pragma unroll
            for (int o = 1; o < 64; o <<= 1) sl += __shfl_xor(sl, o, 64);
            if (lane == 0) {
                __hip_atomic_store(&strip_sum[slot], sl,
                                   __ATOMIC_RELAXED, __HIP_MEMORY_SCOPE_AGENT);
                unsigned int fo = __hip_atomic_fetch_add(
                    &g_fin_cnt, 1u, __ATOMIC_RELAXED, __HIP_MEMORY_SCOPE_AGENT);
                if (fo == 2u * NTJ - 1u) {
                    __hip_atomic_fetch_add(&g_fin_cnt, 0u - 2u * (unsigned)NTJ,
                                           __ATOMIC_RELAXED, __HIP_MEMORY_SCOPE_AGENT);
                    float tot = 0.f;
#pragma unroll
                    for (int b = 0; b < 2 * NTJ; ++b)
                        tot += __hip_atomic_load(&strip_sum[b],
                                 __ATOMIC_RELAXED, __HIP_MEMORY_SCOPE_AGENT);
                    out[0] = tot / (float)N;
                }
            }
        }
    }
}

extern "C" void kernel_launch(void* const* d_in, const int* in_sizes, int n_in,
                              void* d_out, int out_size, void* d_ws, size_t ws_size,
                              hipStream_t stream) {
    const float* in = (const float*)d_in[0];
    const int* tg = (const int*)d_in[1];
    float* out = (float*)d_out;

    unsigned short* xnb = (unsigned short*)d_ws;     // N*D bf16 (2 MB)
    float* sq = (float*)(xnb + (size_t)N * D);       // N floats
    int* ap = (int*)(sq + N);                        // N ints
    int* an = ap + N;                                // N ints
    float* strip_sum = (float*)(an + N);             // 64 floats

    k_norm<<<N / 4, 256, 0, stream>>>(in, xnb, sq, ap, an);
    k_tile<<<dim3(NTJ, NTJ), 256, 0, stream>>>(xnb, sq, tg, ap, an,
                                               strip_sum, out);
}

// Round 7
// 72.709 us; speedup vs baseline: 2.7388x; 1.0823x over previous
//
#include <hip/hip_runtime.h>
#include <math.h>

#define N 4096
#define D 256
#define HALF 2048
#define MARGIN 0.3f

#define BM 64        // block tile (rows == cols)

typedef __attribute__((ext_vector_type(8))) short bf16x8;  // 8 bf16 = 4 VGPRs
typedef __attribute__((ext_vector_type(4))) float f32x4;   // MFMA C/D

typedef __attribute__((address_space(1))) const unsigned int gas_uint;
typedef __attribute__((address_space(3))) unsigned int las_uint;

__device__ __forceinline__ void gld16(const unsigned short* g, unsigned short* l) {
    // async global->LDS, 16 B per lane; LDS dest = wave-uniform base + lane*16
    __builtin_amdgcn_global_load_lds((gas_uint*)g, (las_uint*)l, 16, 0, 0);
}

__device__ __forceinline__ unsigned short f2bf(float x) {
    unsigned int u = __float_as_uint(x);
    return (unsigned short)((u + 0x7fffu + ((u >> 16) & 1u)) >> 16);
}

// ---------------------------------------------------------------------------
// Kernel 1: row L2-normalize -> bf16, plus sq (fp32) and ap/an init.
// One wave per row: float4 load, 6-step shfl_xor reduce, no LDS, no barrier.
// ---------------------------------------------------------------------------
__global__ __launch_bounds__(256) void k_norm(const float* __restrict__ in,
                                              unsigned short* __restrict__ xnb,
                                              float* __restrict__ sq,
                                              int* __restrict__ ap,
                                              int* __restrict__ an) {
    const int row = blockIdx.x * 4 + (threadIdx.x >> 6);
    const int lane = threadIdx.x & 63;
    const float4 v = *(const float4*)&in[(size_t)row * D + lane * 4];
    float s = v.x * v.x + v.y * v.y + v.z * v.z + v.w * v.w;
#pragma unroll
    for (int o = 1; o < 64; o <<= 1) s += __shfl_xor(s, o, 64);
    float nrm = sqrtf(s);
    float inv = 1.0f / (nrm + 1e-6f);
    ushort4 o4;
    o4.x = f2bf(v.x * inv);
    o4.y = f2bf(v.y * inv);
    o4.z = f2bf(v.z * inv);
    o4.w = f2bf(v.w * inv);
    *(ushort4*)&xnb[(size_t)row * D + lane * 4] = o4;
    if (lane == 0) {
        float q = nrm * inv;
        sq[row] = q * q;
        ap[row] = 0;            // == bits(0.0f), the pos_any-false fallback
        an[row] = 0x7f800000;   // +inf sentinel for neg_any-false
    }
}

// ---------------------------------------------------------------------------
// Kernel 2: bf16-MFMA cross-Gram (first half x second half^T) fused with
// masked row/col max-min. Full-K LDS staging (single barrier) via
// global_load_lds, XOR-swizzled via the SOURCE address (LDS stays linear):
//   slot s holds element (row = s>>5, colgrp = (s&31) ^ (row&7));
//   read (r,c) at slot r*32 + (c ^ (r&7)).
// ---------------------------------------------------------------------------
__global__ __launch_bounds__(256, 2) void k_tile(const unsigned short* __restrict__ xnb,
                                                 const float* __restrict__ sq,
                                                 const int* __restrict__ tg,
                                                 int* __restrict__ ap,
                                                 int* __restrict__ an) {
    __shared__ unsigned short As[BM * D];   // 32 KB
    __shared__ unsigned short Bs[BM * D];   // 32 KB
    __shared__ int sra[BM], srn[BM], sca[BM], scn[BM];

    const int bi = blockIdx.y, bj = blockIdx.x;
    const int I0 = bi * BM;   // first-half rows
    const int J0 = bj * BM;   // second-half rows (= output cols)
    const int tid = threadIdx.x;
    const int wave = tid >> 6, lane = tid & 63;
    const int wm = wave >> 1, wn = wave & 1;   // 2x2 wave grid, 32x32 each
    const int lrow = lane & 15, lquad = lane >> 4;

    const unsigned short* Ag = xnb + (size_t)I0 * D;
    const unsigned short* Bg = xnb + (size_t)(HALF + J0) * D;

    // ---- stage full 64x256 tiles, pre-swizzled source, linear LDS dest ----
#pragma unroll
    for (int i = 0; i < 8; ++i) {
        const int ch = i * 4 + wave;           // 1 KB chunk index, wave-uniform
        const int e = ch * 64 + lane;          // this lane's linear 16B slot
        const int row = e >> 5;
        const int sc = (e & 31) ^ (row & 7);   // inverse-swizzled source colgrp
        gld16(Ag + row * D + sc * 8, &As[ch * 512]);
        gld16(Bg + row * D + sc * 8, &Bs[ch * 512]);
    }
    if (tid < BM) {           // init LDS reducers while loads fly
        sra[tid] = 0; srn[tid] = 0x7f800000;
        sca[tid] = 0; scn[tid] = 0x7f800000;
    }
    asm volatile("s_waitcnt vmcnt(0)" ::: "memory");
    __syncthreads();

    // ---- single uninterrupted ds_read + MFMA stream over full K ----------
    f32x4 acc[2][2];
#pragma unroll
    for (int a = 0; a < 2; ++a)
#pragma unroll
        for (int b = 0; b < 2; ++b) acc[a][b] = (f32x4){0.f, 0.f, 0.f, 0.f};

#pragma unroll
    for (int kk = 0; kk < 8; ++kk) {
        bf16x8 af[2], bfr[2];
#pragma unroll
        for (int mi = 0; mi < 2; ++mi) {
            const int r = wm * 32 + mi * 16 + lrow;
            const int s = r * 32 + ((kk * 4 + lquad) ^ (r & 7));
            af[mi] = *(const bf16x8*)&As[s * 8];
        }
#pragma unroll
        for (int nj = 0; nj < 2; ++nj) {
            const int r = wn * 32 + nj * 16 + lrow;
            const int s = r * 32 + ((kk * 4 + lquad) ^ (r & 7));
            bfr[nj] = *(const bf16x8*)&Bs[s * 8];
        }
#pragma unroll
        for (int mi = 0; mi < 2; ++mi)
#pragma unroll
            for (int nj = 0; nj < 2; ++nj)
                acc[mi][nj] = __builtin_amdgcn_mfma_f32_16x16x32_bf16(
                    af[mi], bfr[nj], acc[mi][nj], 0, 0, 0);
    }

    // ---- epilogue: distances + masked max/min -----------------------------
    // C/D layout: col = lane&15, row = lquad*4 + reg   (per 16x16 tile)
    float sqi[2][4], sqj[2];
    int tgi[2][4], tgj[2];
#pragma unroll
    for (int mi = 0; mi < 2; ++mi)
#pragma unroll
        for (int r = 0; r < 4; ++r) {
            int gi = I0 + wm * 32 + mi * 16 + lquad * 4 + r;
            sqi[mi][r] = sq[gi];
            tgi[mi][r] = tg[gi];
        }
#pragma unroll
    for (int nj = 0; nj < 2; ++nj) {
        int gj = HALF + J0 + wn * 32 + nj * 16 + lrow;
        sqj[nj] = sq[gj];
        tgj[nj] = tg[gj];
    }

    const float INF = __int_as_float(0x7f800000);
    float rap[2][4], ran[2][4], capv[2], canv[2];
#pragma unroll
    for (int mi = 0; mi < 2; ++mi)
#pragma unroll
        for (int r = 0; r < 4; ++r) { rap[mi][r] = 0.f; ran[mi][r] = INF; }
#pragma unroll
    for (int nj = 0; nj < 2; ++nj) { capv[nj] = 0.f; canv[nj] = INF; }

#pragma unroll
    for (int mi = 0; mi < 2; ++mi)
#pragma unroll
        for (int nj = 0; nj < 2; ++nj)
#pragma unroll
            for (int r = 0; r < 4; ++r) {
                float d2 = sqi[mi][r] + sqj[nj] - 2.0f * acc[mi][nj][r];
                float d = sqrtf(fmaxf(d2, 1e-6f));
                if (tgi[mi][r] == tgj[nj]) {
                    rap[mi][r] = fmaxf(rap[mi][r], d);
                    capv[nj] = fmaxf(capv[nj], d);
                } else {
                    ran[mi][r] = fminf(ran[mi][r], d);
                    canv[nj] = fminf(canv[nj], d);
                }
            }

    // shuffle pre-reduce: rows across the 16 lanes sharing lquad
#pragma unroll
    for (int mi = 0; mi < 2; ++mi)
#pragma unroll
        for (int r = 0; r < 4; ++r) {
#pragma unroll
            for (int o = 1; o < 16; o <<= 1) {
                rap[mi][r] = fmaxf(rap[mi][r], __shfl_xor(rap[mi][r], o, 64));
                ran[mi][r] = fminf(ran[mi][r], __shfl_xor(ran[mi][r], o, 64));
            }
        }
    // cols across the 4 quads
#pragma unroll
    for (int nj = 0; nj < 2; ++nj) {
#pragma unroll
        for (int o = 16; o < 64; o <<= 1) {
            capv[nj] = fmaxf(capv[nj], __shfl_xor(capv[nj], o, 64));
            canv[nj] = fminf(canv[nj], __shfl_xor(canv[nj], o, 64));
        }
    }

    if (lrow == 0) {  // one lane per row; 2-way contention (wn)
#pragma unroll
        for (int mi = 0; mi < 2; ++mi)
#pragma unroll
            for (int r = 0; r < 4; ++r) {
                int lr = wm * 32 + mi * 16 + lquad * 4 + r;
                atomicMax(&sra[lr], __float_as_int(rap[mi][r]));
                atomicMin(&srn[lr], __float_as_int(ran[mi][r]));
            }
    }
    if (lquad == 0) {  // one lane per col; 2-way contention (wm)
#pragma unroll
        for (int nj = 0; nj < 2; ++nj) {
            int lc = wn * 32 + nj * 16 + lrow;
            atomicMax(&sca[lc], __float_as_int(capv[nj]));
            atomicMin(&scn[lc], __float_as_int(canv[nj]));
        }
    }
    __syncthreads();
    if (tid < BM) {
        atomicMax(&ap[I0 + tid], sra[tid]);
        atomicMin(&an[I0 + tid], srn[tid]);
        atomicMax(&ap[HALF + J0 + tid], sca[tid]);
        atomicMin(&an[HALF + J0 + tid], scn[tid]);
    }
}

// ---------------------------------------------------------------------------
// Kernel 3: loss = mean(relu(ap - an' + margin)); an' = (an==+inf ? 1 : an)
// ---------------------------------------------------------------------------
__global__ __launch_bounds__(1024) void k_loss(const int* __restrict__ ap,
                                               const int* __restrict__ an,
                                               float* __restrict__ out) {
    const int t = threadIdx.x;  // single block of 1024
    float s = 0.f;
#pragma unroll
    for (int i = t; i < N; i += 1024) {
        float dap = __int_as_float(ap[i]);
        int anb = an[i];
        float dan = (anb == 0x7f800000) ? 1.0f : __int_as_float(anb);
        float v = dap - dan + MARGIN;
        s += (v > 0.f) ? v : 0.f;
    }
#pragma unroll
    for (int o = 32; o > 0; o >>= 1) s += __shfl_down(s, o, 64);
    __shared__ float wsum[16];
    if ((t & 63) == 0) wsum[t >> 6] = s;
    __syncthreads();
    if (t == 0) {
        float tot = 0.f;
#pragma unroll
        for (int w = 0; w < 16; ++w) tot += wsum[w];
        out[0] = tot / (float)N;
    }
}

extern "C" void kernel_launch(void* const* d_in, const int* in_sizes, int n_in,
                              void* d_out, int out_size, void* d_ws, size_t ws_size,
                              hipStream_t stream) {
    const float* in = (const float*)d_in[0];
    const int* tg = (const int*)d_in[1];
    float* out = (float*)d_out;

    unsigned short* xnb = (unsigned short*)d_ws;   // N*D bf16 (2 MB)
    float* sq = (float*)(xnb + (size_t)N * D);     // N floats
    int* ap = (int*)(sq + N);                      // N ints
    int* an = ap + N;                              // N ints

    k_norm<<<N / 4, 256, 0, stream>>>(in, xnb, sq, ap, an);
    k_tile<<<dim3(HALF / BM, HALF / BM), 256, 0, stream>>>(xnb, sq, tg, ap, an);
    k_loss<<<1, 1024, 0, stream>>>(ap, an, out);
}